// Round 15
// baseline (431.568 us; speedup 1.0000x reference)
//
#include <hip/hip_runtime.h>
#include <hip/hip_fp16.h>

#define N_NODES 50000
#define N_EDGES 1600000
#define DIM     128
#define NLAYERS 3
#define NGRAPHS 64

#define NBUCK   196            // buckets of 256 nodes: bucket = dst >> 8
#define CSR_BLKS 256
#define EPB     (N_EDGES / CSR_BLKS)   // 6250 edges per csr block
#define EITER   ((EPB + 255) / 256)    // 25

typedef _Float16 half8 __attribute__((ext_vector_type(8)));
typedef float    f32x4 __attribute__((ext_vector_type(4)));

#define LDK 136   // padded halves/row: 272B stride (16B-aligned), rotates banks

// ---------------------------------------------------------------- setup
__global__ __launch_bounds__(256) void setup_kernel(
        const float* __restrict__ X, __half* __restrict__ Xh,
        const float* __restrict__ Wd, const float* __restrict__ Wc,
        const float* __restrict__ Ws, __half* __restrict__ WT,
        float* __restrict__ sums, int* __restrict__ gcnt) {
    int i = blockIdx.x * 256 + threadIdx.x;
    if (i < N_NODES * DIM / 4) {
        float4 v = *(const float4*)(X + (size_t)i * 4);
        union { __half2 h2[2]; uint2 u; } pk;
        pk.h2[0] = __floats2half2_rn(v.x, v.y);
        pk.h2[1] = __floats2half2_rn(v.z, v.w);
        *(uint2*)(Xh + (size_t)i * 4) = pk.u;
    }
    if (i < 9 * DIM * DIM) {   // WT[(l*3+w)][n][k] = W[l][k][n]
        int k  = i & 127;
        int n  = (i >> 7) & 127;
        int lw = i >> 14;
        int l  = lw / 3, w = lw - 3 * l;
        const float* W = ((w == 0) ? Wd : (w == 1) ? Wc : Ws)
                         + (size_t)l * DIM * DIM;
        WT[i] = __float2half(W[k * DIM + n]);
    }
    if (i < NGRAPHS * DIM) sums[i] = 0.f;
    if (i < NGRAPHS) gcnt[i] = 0;
}

// ---------------------------------------------------------------- CSR build
// Two-level counting sort, zero global atomics (R7 lesson: 1.6M device
// atomics cost 56 MB HBM RMW regardless of locality).
__global__ __launch_bounds__(256) void csr1_kernel(const int* __restrict__ dst,
                                                   int* __restrict__ cntmat) {
    __shared__ int hc[NBUCK];
    int tid = threadIdx.x;
    for (int i = tid; i < NBUCK; i += 256) hc[i] = 0;
    __syncthreads();
    int base = blockIdx.x * EPB;
#pragma unroll
    for (int i = 0; i < EITER; ++i) {
        int idx = i * 256 + tid;
        if (idx < EPB) atomicAdd(&hc[dst[base + idx] >> 8], 1);
    }
    __syncthreads();
    for (int i = tid; i < NBUCK; i += 256)
        cntmat[i * CSR_BLKS + blockIdx.x] = hc[i];
}

__global__ __launch_bounds__(256) void scanA_kernel(const int* __restrict__ cntmat,
                                                    int* __restrict__ exc,
                                                    int* __restrict__ btot) {
    __shared__ int sh[256];
    int tid = threadIdx.x, b = blockIdx.x;
    int v = cntmat[b * CSR_BLKS + tid];
    sh[tid] = v;
    __syncthreads();
    for (int o = 1; o < 256; o <<= 1) {
        int t = (tid >= o) ? sh[tid - o] : 0;
        __syncthreads();
        sh[tid] += t;
        __syncthreads();
    }
    exc[b * CSR_BLKS + tid] = sh[tid] - v;
    if (tid == 255) btot[b] = sh[255];
}

// scanB folded in — every block redundantly LDS-scans btot[196] (~1us);
// block 0 publishes bstart for csr3.
__global__ __launch_bounds__(256) void csr2_kernel(const int* __restrict__ src,
                                                   const int* __restrict__ dst,
                                                   const int* __restrict__ et,
                                                   const int* __restrict__ exc,
                                                   const int* __restrict__ btot,
                                                   int* __restrict__ bstart,
                                                   int* __restrict__ esv,
                                                   unsigned short* __restrict__ edst) {
    __shared__ int sh[256];
    __shared__ int bst[NBUCK];
    __shared__ int cur[NBUCK];
    int tid = threadIdx.x;
    int v = (tid < NBUCK) ? btot[tid] : 0;
    sh[tid] = v;
    __syncthreads();
    for (int o = 1; o < 256; o <<= 1) {
        int t = (tid >= o) ? sh[tid - o] : 0;
        __syncthreads();
        sh[tid] += t;
        __syncthreads();
    }
    if (tid < NBUCK) bst[tid] = sh[tid] - v;
    if (blockIdx.x == 0) {
        if (tid < NBUCK) bstart[tid] = sh[tid] - v;
        if (tid == NBUCK - 1) bstart[NBUCK] = sh[tid];
    }
    __syncthreads();
    if (tid < NBUCK) cur[tid] = exc[tid * CSR_BLKS + blockIdx.x] + bst[tid];
    __syncthreads();
    int base = blockIdx.x * EPB;
#pragma unroll
    for (int i = 0; i < EITER; ++i) {
        int idx = i * 256 + tid;
        if (idx < EPB) {
            int e = base + idx;
            int d = dst[e];
            int pos = atomicAdd(&cur[d >> 8], 1);
            esv[pos]  = src[e] + et[e] * N_NODES;
            edst[pos] = (unsigned short)d;
        }
    }
}

// phase 4 (R10/R14-proven): per-bucket finalize with TYPE-SEGMENTED rows —
// data edges first, control after (two LDS cursors). col stores raw src;
// emits ndeg (data in-degree) for the fused-GEMM bias term.
__global__ __launch_bounds__(256) void csr3_kernel(const int* __restrict__ esv,
                                                   const unsigned short* __restrict__ edst,
                                                   const int* __restrict__ bstart,
                                                   int* __restrict__ col,
                                                   int* __restrict__ row_start,
                                                   int* __restrict__ deg,
                                                   int* __restrict__ ndeg) {
    __shared__ int cnt[256];
    __shared__ int cntd[256];
    __shared__ int sh[256];
    __shared__ int curd[256];
    __shared__ int curc[256];
    int tid = threadIdx.x, b = blockIdx.x;
    int bs = bstart[b], be = bstart[b + 1];
    cnt[tid] = 0;
    cntd[tid] = 0;
    __syncthreads();
    for (int e = bs + tid; e < be; e += 256) {
        int nd_ = edst[e] & 255;
        atomicAdd(&cnt[nd_], 1);
        if (esv[e] < N_NODES) atomicAdd(&cntd[nd_], 1);
    }
    __syncthreads();
    int v = cnt[tid];
    sh[tid] = v;
    __syncthreads();
    for (int o = 1; o < 256; o <<= 1) {
        int t = (tid >= o) ? sh[tid - o] : 0;
        __syncthreads();
        sh[tid] += t;
        __syncthreads();
    }
    int off  = sh[tid] - v;
    int node = (b << 8) + tid;
    if (node < N_NODES) {
        row_start[node] = bs + off;
        deg[node]       = v;
        ndeg[node]      = cntd[tid];
    }
    curd[tid] = bs + off;
    curc[tid] = bs + off + cntd[tid];
    __syncthreads();
    for (int e = bs + tid; e < be; e += 256) {
        int d  = edst[e] & 255;
        int sv = esv[e];
        int pos;
        if (sv < N_NODES) pos = atomicAdd(&curd[d], 1);
        else            { pos = atomicAdd(&curc[d], 1); sv -= N_NODES; }
        col[pos] = sv;
    }
}

// ---------------------------------------------------------------- aggregation
// R15 slot-split: half-wave per node (R13 grid/issue shape), gathers RAW X
// (12.8 MB source: per-XCD distinct-row floor ~100 MB vs Xdc's 176). Burst
// of 8 where slots 0-3 walk the DATA segment, slots 4-7 the CONTROL segment
// -> accumulators split naturally (Sd = slots 0-3, Sc = 4-7). VGPR ~40 and
// MLP 8 both unchanged vs R13 (R14 lesson: issue overhead eats byte wins).
__global__ __launch_bounds__(256) void agg_kernel(
        const int* __restrict__ row_start, const int* __restrict__ ndeg_arr,
        const int* __restrict__ deg_arr, const int* __restrict__ col,
        const __half* __restrict__ Xh,
        __half* __restrict__ Sd, __half* __restrict__ Sc) {
    int wave = (blockIdx.x * 256 + threadIdx.x) >> 6;
    int lane = threadIdx.x & 63;
    int half = lane >> 5;
    int l32  = lane & 31;
    int node = wave * 2 + half;
    if (node >= N_NODES) return;

    int rs = row_start[node];
    int nd = ndeg_arr[node];
    int dg = deg_arr[node];
    int nc = dg - nd;
    const size_t off = (size_t)l32 * 4;   // in halves

    float4 a[8];
#pragma unroll
    for (int i = 0; i < 8; ++i) a[i] = make_float4(0.f, 0.f, 0.f, 0.f);

    int nmax = (nd > nc) ? nd : nc;
    int nb   = (nmax + 3) >> 2;
    int cd   = (nd > 0) ? nd - 1 : 0;    // clamp caps (segment may be empty;
    int cc   = (nc > 0) ? nc - 1 : 0;    // masked slots only need a VALID addr)
    int bc   = rs + nd;                  // control-segment base
    for (int b = 0; b < nb; ++b) {
        int e0 = b * 4;
        int p[8];
#pragma unroll
        for (int i = 0; i < 4; ++i) {
            int rd = e0 + i; rd = (rd < cd) ? rd : cd;
            int rc = e0 + i; rc = (rc < cc) ? rc : cc;
            int id = rs + rd;
            int ic = bc + rc;
            p[i]     = col[(id < N_EDGES) ? id : (N_EDGES - 1)];
            p[i + 4] = col[(ic < N_EDGES) ? ic : (N_EDGES - 1)];
        }
        union { uint2 u; __half2 h2[2]; } v[8];
#pragma unroll
        for (int i = 0; i < 8; ++i)
            v[i].u = *(const uint2*)(Xh + (size_t)p[i] * DIM + off);
#pragma unroll
        for (int i = 0; i < 4; ++i) {
            if (e0 + i >= nd) { v[i].u.x = 0u; v[i].u.y = 0u; }
            if (e0 + i >= nc) { v[i + 4].u.x = 0u; v[i + 4].u.y = 0u; }
        }
#pragma unroll
        for (int i = 0; i < 8; ++i) {
            float2 f0 = __half22float2(v[i].h2[0]);
            float2 f1 = __half22float2(v[i].h2[1]);
            a[i].x += f0.x; a[i].y += f0.y;
            a[i].z += f1.x; a[i].w += f1.y;
        }
    }

    float4 sd, sc;
    sd.x = a[0].x + a[1].x + a[2].x + a[3].x;
    sd.y = a[0].y + a[1].y + a[2].y + a[3].y;
    sd.z = a[0].z + a[1].z + a[2].z + a[3].z;
    sd.w = a[0].w + a[1].w + a[2].w + a[3].w;
    sc.x = a[4].x + a[5].x + a[6].x + a[7].x;
    sc.y = a[4].y + a[5].y + a[6].y + a[7].y;
    sc.z = a[4].z + a[5].z + a[6].z + a[7].z;
    sc.w = a[4].w + a[5].w + a[6].w + a[7].w;

    union { __half2 h2[2]; uint2 u; } pk;
    pk.h2[0] = __floats2half2_rn(sd.x, sd.y);
    pk.h2[1] = __floats2half2_rn(sd.z, sd.w);
    *(uint2*)(Sd + (size_t)node * DIM + off) = pk.u;
    pk.h2[0] = __floats2half2_rn(sc.x, sc.y);
    pk.h2[1] = __floats2half2_rn(sc.z, sc.w);
    *(uint2*)(Sc + (size_t)node * DIM + off) = pk.u;
}

// ---------------------------------------------------------------- fused GEMM
// R15 split-N: X' = relu(Sd@Wd + Sc@Wc + X@Ws + nd*bd + nc*bc + bs).
// Grid (1563, 2): block = 32 rows x 64 cols. LDS = 3 A-tiles (25.5 KB) +
// half-B (17 KB) = 42.5 KB -> 3 blocks/CU (fixes R14 gemm3f's 61 KB ->
// 2/CU penalty). Wave = 16 cols, acc[2] (32x16), 24 MFMAs.
__global__ __launch_bounds__(256) void gemm3f_kernel(
        const __half* __restrict__ Xh, const __half* __restrict__ Sd,
        const __half* __restrict__ Sc,
        const __half* __restrict__ WTl,  // [3][n][k] fp16: Wd, Wc, Ws
        const float* __restrict__ bd, const float* __restrict__ bc,
        const float* __restrict__ bs,
        const int* __restrict__ ndeg, const int* __restrict__ deg,
        __half* __restrict__ Xout) {
    __shared__ _Float16 Ad[32 * LDK];
    __shared__ _Float16 Ac[32 * LDK];
    __shared__ _Float16 Ax[32 * LDK];
    __shared__ _Float16 Bs_[64 * LDK];

    const int tid = threadIdx.x;
    const int m0  = blockIdx.x * 32;
    const int ch  = blockIdx.y;          // column half: cols [ch*64, ch*64+64)

    const __half* Asrc[3] = {Sd, Sc, Xh};
    _Float16* Atile[3]    = {Ad, Ac, Ax};
#pragma unroll
    for (int t = 0; t < 3; ++t) {
#pragma unroll
        for (int i = 0; i < 2; ++i) {
            int c    = i * 256 + tid;
            int row  = c >> 4;
            int colh = (c & 15) * 8;
            uint4 v  = make_uint4(0u, 0u, 0u, 0u);
            int gr   = m0 + row;
            if (gr < N_NODES)
                v = *(const uint4*)(Asrc[t] + (size_t)gr * DIM + colh);
            *(uint4*)(Atile[t] + row * LDK + colh) = v;
        }
    }

    const int wv = tid >> 6;             // wave -> cols wv*16..wv*16+15 (of 64)
    const int l  = tid & 63;
    const int lm = l & 15;
    const int q  = l >> 4;

    f32x4 acc[2];
    acc[0] = (f32x4){0.f, 0.f, 0.f, 0.f};
    acc[1] = (f32x4){0.f, 0.f, 0.f, 0.f};

    for (int w = 0; w < 3; ++w) {
        __syncthreads();   // protects Bs_ reuse (and A-tiles on first pass)
        const __half* Wt = WTl + (size_t)w * DIM * DIM + (size_t)ch * 64 * DIM;
#pragma unroll
        for (int i = 0; i < 4; ++i) {
            int c    = i * 256 + tid;
            int row  = c >> 4;           // 0..63
            int colh = (c & 15) * 8;
            uint4 v = *(const uint4*)(Wt + (size_t)row * DIM + colh);
            *(uint4*)(Bs_ + row * LDK + colh) = v;
        }
        __syncthreads();
        const _Float16* A = Atile[w];
#pragma unroll
        for (int ks = 0; ks < 4; ++ks) {
            int coff = ks * 32 + q * 8;
            half8 a0 = *(const half8*)(A + lm * LDK + coff);
            half8 a1 = *(const half8*)(A + (16 + lm) * LDK + coff);
            half8 bb = *(const half8*)(Bs_ + (wv * 16 + lm) * LDK + coff);
            acc[0] = __builtin_amdgcn_mfma_f32_16x16x32_f16(a0, bb, acc[0], 0, 0, 0);
            acc[1] = __builtin_amdgcn_mfma_f32_16x16x32_f16(a1, bb, acc[1], 0, 0, 0);
        }
    }

    // epilogue: + nd*bd + nc*bc + bs, relu, fp16 store
    int colg  = ch * 64 + wv * 16 + lm;
    float bdv = bd[colg], bcv = bc[colg], bsv = bs[colg];
#pragma unroll
    for (int mt = 0; mt < 2; ++mt) {
#pragma unroll
        for (int r = 0; r < 4; ++r) {
            int row = m0 + mt * 16 + q * 4 + r;
            if (row < N_NODES) {
                float ndf = (float)ndeg[row];
                float ncf = (float)(deg[row] - ndeg[row]);
                float v = acc[mt][r] + ndf * bdv + ncf * bcv + bsv;
                Xout[(size_t)row * DIM + colg] = __float2half(fmaxf(v, 0.f));
            }
        }
    }
}

// ---------------------------------------------------------------- pooling
// R13-proven: 782 blocks, 8 row-streams x 32 lanes, uint2 loads, LDS bucket
// flush. NO device-scope fence (R12/R13 lesson: per-block __threadfence()
// across a 782-block grid costs ~50us). div is its own launch.
__global__ __launch_bounds__(256) void pool_kernel(const __half* __restrict__ X,
                                                   const int* __restrict__ bid,
                                                   float* __restrict__ sums,
                                                   int* __restrict__ gcnt) {
    __shared__ float acc[8][DIM];
    __shared__ int scnt[8];
    __shared__ int sgmin;
    int tid = threadIdx.x;
    for (int i = tid; i < 8 * DIM; i += 256) ((float*)acc)[i] = 0.f;
    if (tid < 8) scnt[tid] = 0;
    int n0 = blockIdx.x * 64;
    if (tid == 0) sgmin = bid[n0];
    __syncthreads();
    int gmin = sgmin;

    int s    = tid >> 5;
    int lane = tid & 31;
    int r0   = n0 + s * 8;

    int g[8];
    union { uint2 u; __half2 h2[2]; } v[8];
#pragma unroll
    for (int i = 0; i < 8; ++i) {
        int r = r0 + i;
        g[i] = (r < N_NODES) ? bid[r] : -1;
    }
#pragma unroll
    for (int i = 0; i < 8; ++i) {
        int r = r0 + i;
        if (r < N_NODES)
            v[i].u = *(const uint2*)(X + (size_t)r * DIM + lane * 4);
        else { v[i].u.x = 0u; v[i].u.y = 0u; }
    }

    float4 a = make_float4(0.f, 0.f, 0.f, 0.f);
    int cur = -1, run = 0;
#pragma unroll
    for (int i = 0; i < 8; ++i) {
        if (g[i] != cur) {
            if (cur >= 0) {
                int slot = cur - gmin;
                if (slot < 8) {
                    atomicAdd(&acc[slot][lane * 4 + 0], a.x);
                    atomicAdd(&acc[slot][lane * 4 + 1], a.y);
                    atomicAdd(&acc[slot][lane * 4 + 2], a.z);
                    atomicAdd(&acc[slot][lane * 4 + 3], a.w);
                    if (lane == 0) atomicAdd(&scnt[slot], run);
                } else {
                    atomicAdd(&sums[cur * DIM + lane * 4 + 0], a.x);
                    atomicAdd(&sums[cur * DIM + lane * 4 + 1], a.y);
                    atomicAdd(&sums[cur * DIM + lane * 4 + 2], a.z);
                    atomicAdd(&sums[cur * DIM + lane * 4 + 3], a.w);
                    if (lane == 0) atomicAdd(&gcnt[cur], run);
                }
            }
            cur = g[i];
            a = make_float4(0.f, 0.f, 0.f, 0.f);
            run = 0;
        }
        if (g[i] >= 0) {
            float2 f0 = __half22float2(v[i].h2[0]);
            float2 f1 = __half22float2(v[i].h2[1]);
            a.x += f0.x; a.y += f0.y; a.z += f1.x; a.w += f1.y;
            run++;
        }
    }
    if (cur >= 0) {
        int slot = cur - gmin;
        if (slot < 8) {
            atomicAdd(&acc[slot][lane * 4 + 0], a.x);
            atomicAdd(&acc[slot][lane * 4 + 1], a.y);
            atomicAdd(&acc[slot][lane * 4 + 2], a.z);
            atomicAdd(&acc[slot][lane * 4 + 3], a.w);
            if (lane == 0) atomicAdd(&scnt[slot], run);
        } else {
            atomicAdd(&sums[cur * DIM + lane * 4 + 0], a.x);
            atomicAdd(&sums[cur * DIM + lane * 4 + 1], a.y);
            atomicAdd(&sums[cur * DIM + lane * 4 + 2], a.z);
            atomicAdd(&sums[cur * DIM + lane * 4 + 3], a.w);
            if (lane == 0) atomicAdd(&gcnt[cur], run);
        }
    }
    __syncthreads();

    for (int slot = 0; slot < 8; ++slot) {
        if (scnt[slot] > 0) {
            int gg = gmin + slot;
            for (int i = tid; i < DIM; i += 256)
                atomicAdd(&sums[gg * DIM + i], acc[slot][i]);
            if (tid == 0) atomicAdd(&gcnt[gg], scnt[slot]);
        }
    }
}

__global__ __launch_bounds__(256) void div_kernel(const float* __restrict__ sums,
                                                  const int* __restrict__ gcnt,
                                                  float* __restrict__ out) {
    int i = blockIdx.x * 256 + threadIdx.x;
    if (i < NGRAPHS * DIM) {
        int g = i >> 7;
        out[i] = sums[i] / fmaxf((float)gcnt[g], 1.f);
    }
}

// ---------------------------------------------------------------- launcher
extern "C" void kernel_launch(void* const* d_in, const int* in_sizes, int n_in,
                              void* d_out, int out_size, void* d_ws, size_t ws_size,
                              hipStream_t stream) {
    const float* Xin = (const float*)d_in[0];
    const float* Wd  = (const float*)d_in[1];
    const float* bd  = (const float*)d_in[2];
    const float* Wc  = (const float*)d_in[3];
    const float* bc  = (const float*)d_in[4];
    const float* Ws  = (const float*)d_in[5];
    const float* bs  = (const float*)d_in[6];
    const int* edge_index = (const int*)d_in[7];
    const int* edge_types = (const int*)d_in[8];
    const int* batch_ids  = (const int*)d_in[9];

    const int* src = edge_index;
    const int* dst = edge_index + N_EDGES;

    const size_t NBH = (size_t)N_NODES * DIM * sizeof(__half);  // 12.8 MB
    char* w = (char*)d_ws;
    auto take = [&](size_t bytes) {
        char* p = w;
        w += (bytes + 255) & ~(size_t)255;
        return p;
    };
    __half* X0h  = (__half*)take(NBH);
    __half* Xb0h = (__half*)take(NBH);
    __half* Xb1h = (__half*)take(NBH);
    __half* Sdb  = (__half*)take(NBH);
    __half* Scb  = (__half*)take(NBH);
    __half* WT   = (__half*)take((size_t)9 * DIM * DIM * sizeof(__half));
    int* col     = (int*)take((size_t)N_EDGES * 4);
    int* esv     = (int*)take((size_t)N_EDGES * 4);
    unsigned short* edst = (unsigned short*)take((size_t)N_EDGES * 2);
    int* cntmat  = (int*)take((size_t)NBUCK * CSR_BLKS * 4);
    int* exc     = (int*)take((size_t)NBUCK * CSR_BLKS * 4);
    int* btot    = (int*)take((size_t)NBUCK * 4);
    int* bstart  = (int*)take((size_t)(NBUCK + 1) * 4);
    int* rowst   = (int*)take((size_t)N_NODES * 4);
    int* deg     = (int*)take((size_t)N_NODES * 4);
    int* ndeg    = (int*)take((size_t)N_NODES * 4);
    float* sums  = (float*)take((size_t)NGRAPHS * DIM * 4);
    int* gcnt    = (int*)take(NGRAPHS * 4);

    setup_kernel<<<(N_NODES * DIM / 4 + 255) / 256, 256, 0, stream>>>(
        Xin, X0h, Wd, Wc, Ws, WT, sums, gcnt);

    csr1_kernel<<<CSR_BLKS, 256, 0, stream>>>(dst, cntmat);
    scanA_kernel<<<NBUCK, 256, 0, stream>>>(cntmat, exc, btot);
    csr2_kernel<<<CSR_BLKS, 256, 0, stream>>>(src, dst, edge_types, exc,
                                              btot, bstart, esv, edst);
    csr3_kernel<<<NBUCK, 256, 0, stream>>>(esv, edst, bstart, col, rowst,
                                           deg, ndeg);

    const int GEMM_MBLK = (N_NODES + 31) / 32;    // 1563
    const int AGG_BLKS  = (N_NODES / 2 + 3) / 4;  // 6250 (2 nodes/wave)
    const __half* Xcur = X0h;
    __half* bufs[3] = {Xb0h, Xb1h, Xb0h};
    for (int l = 0; l < NLAYERS; ++l) {
        agg_kernel<<<AGG_BLKS, 256, 0, stream>>>(rowst, ndeg, deg, col, Xcur,
                                                 Sdb, Scb);
        __half* Xnext = bufs[l];
        gemm3f_kernel<<<dim3(GEMM_MBLK, 2), 256, 0, stream>>>(
            Xcur, Sdb, Scb, WT + (size_t)l * 3 * DIM * DIM,
            bd + (size_t)l * DIM, bc + (size_t)l * DIM, bs + (size_t)l * DIM,
            ndeg, deg, Xnext);
        Xcur = Xnext;
    }

    const int POOL_BLKS = (N_NODES + 63) / 64;  // 782
    pool_kernel<<<POOL_BLKS, 256, 0, stream>>>(Xcur, batch_ids, sums, gcnt);
    div_kernel<<<(NGRAPHS * DIM + 255) / 256, 256, 0, stream>>>(sums, gcnt,
                                                                (float*)d_out);
}

// Round 16
// 385.679 us; speedup vs baseline: 1.1190x; 1.1190x over previous
//
#include <hip/hip_runtime.h>
#include <hip/hip_fp16.h>

#define N_NODES 50000
#define N_EDGES 1600000
#define DIM     128
#define NLAYERS 3
#define NGRAPHS 64

#define NBUCK   196            // buckets of 256 nodes: bucket = dst >> 8
#define CSR_BLKS 256
#define EPB     (N_EDGES / CSR_BLKS)   // 6250 edges per csr block
#define EITER   ((EPB + 255) / 256)    // 25

typedef _Float16 half8 __attribute__((ext_vector_type(8)));
typedef float    f32x4 __attribute__((ext_vector_type(4)));

#define LDK 136   // padded halves/row: 272B stride (16B-aligned), rotates banks

// ---------------------------------------------------------------- setup
__global__ __launch_bounds__(256) void setup_kernel(
        const float* __restrict__ X, __half* __restrict__ Xh,
        const float* __restrict__ Wd, const float* __restrict__ Wc,
        const float* __restrict__ Ws, __half* __restrict__ WT,
        float* __restrict__ sums, int* __restrict__ gcnt) {
    int i = blockIdx.x * 256 + threadIdx.x;
    if (i < N_NODES * DIM / 4) {
        float4 v = *(const float4*)(X + (size_t)i * 4);
        union { __half2 h2[2]; uint2 u; } pk;
        pk.h2[0] = __floats2half2_rn(v.x, v.y);
        pk.h2[1] = __floats2half2_rn(v.z, v.w);
        *(uint2*)(Xh + (size_t)i * 4) = pk.u;
    }
    if (i < 9 * DIM * DIM) {   // WT[(l*3+w)][n][k] = W[l][k][n]
        int k  = i & 127;
        int n  = (i >> 7) & 127;
        int lw = i >> 14;
        int l  = lw / 3, w = lw - 3 * l;
        const float* W = ((w == 0) ? Wd : (w == 1) ? Wc : Ws)
                         + (size_t)l * DIM * DIM;
        WT[i] = __float2half(W[k * DIM + n]);
    }
    if (i < NGRAPHS * DIM) sums[i] = 0.f;
    if (i < NGRAPHS) gcnt[i] = 0;
}

// ---------------------------------------------------------------- CSR build
// Two-level counting sort, zero global atomics (R7 lesson: 1.6M device
// atomics cost 56 MB HBM RMW regardless of locality).
__global__ __launch_bounds__(256) void csr1_kernel(const int* __restrict__ dst,
                                                   int* __restrict__ cntmat) {
    __shared__ int hc[NBUCK];
    int tid = threadIdx.x;
    for (int i = tid; i < NBUCK; i += 256) hc[i] = 0;
    __syncthreads();
    int base = blockIdx.x * EPB;
#pragma unroll
    for (int i = 0; i < EITER; ++i) {
        int idx = i * 256 + tid;
        if (idx < EPB) atomicAdd(&hc[dst[base + idx] >> 8], 1);
    }
    __syncthreads();
    for (int i = tid; i < NBUCK; i += 256)
        cntmat[i * CSR_BLKS + blockIdx.x] = hc[i];
}

__global__ __launch_bounds__(256) void scanA_kernel(const int* __restrict__ cntmat,
                                                    int* __restrict__ exc,
                                                    int* __restrict__ btot) {
    __shared__ int sh[256];
    int tid = threadIdx.x, b = blockIdx.x;
    int v = cntmat[b * CSR_BLKS + tid];
    sh[tid] = v;
    __syncthreads();
    for (int o = 1; o < 256; o <<= 1) {
        int t = (tid >= o) ? sh[tid - o] : 0;
        __syncthreads();
        sh[tid] += t;
        __syncthreads();
    }
    exc[b * CSR_BLKS + tid] = sh[tid] - v;
    if (tid == 255) btot[b] = sh[255];
}

// scanB folded in — every block redundantly LDS-scans btot[196] (~1us);
// block 0 publishes bstart for csr3. R16: edge record packed into ONE int:
// sv = src + et*N (17 bits) | (dst&255)<<17 — kills the edst array
// (-3.2 MB write, -3.2 MB read).
__global__ __launch_bounds__(256) void csr2_kernel(const int* __restrict__ src,
                                                   const int* __restrict__ dst,
                                                   const int* __restrict__ et,
                                                   const int* __restrict__ exc,
                                                   const int* __restrict__ btot,
                                                   int* __restrict__ bstart,
                                                   int* __restrict__ esv) {
    __shared__ int sh[256];
    __shared__ int bst[NBUCK];
    __shared__ int cur[NBUCK];
    int tid = threadIdx.x;
    int v = (tid < NBUCK) ? btot[tid] : 0;
    sh[tid] = v;
    __syncthreads();
    for (int o = 1; o < 256; o <<= 1) {
        int t = (tid >= o) ? sh[tid - o] : 0;
        __syncthreads();
        sh[tid] += t;
        __syncthreads();
    }
    if (tid < NBUCK) bst[tid] = sh[tid] - v;
    if (blockIdx.x == 0) {
        if (tid < NBUCK) bstart[tid] = sh[tid] - v;
        if (tid == NBUCK - 1) bstart[NBUCK] = sh[tid];
    }
    __syncthreads();
    if (tid < NBUCK) cur[tid] = exc[tid * CSR_BLKS + blockIdx.x] + bst[tid];
    __syncthreads();
    int base = blockIdx.x * EPB;
#pragma unroll
    for (int i = 0; i < EITER; ++i) {
        int idx = i * 256 + tid;
        if (idx < EPB) {
            int e = base + idx;
            int d = dst[e];
            int pos = atomicAdd(&cur[d >> 8], 1);
            esv[pos] = (src[e] + et[e] * N_NODES) | ((d & 255) << 17);
        }
    }
}

// phase 4: per-bucket finalize (LDS count -> scan -> row_start/deg ->
// scatter). Bucket's esv slice (~33 KB) stays L2-resident between passes.
__global__ __launch_bounds__(256) void csr3_kernel(const int* __restrict__ esv,
                                                   const int* __restrict__ bstart,
                                                   int* __restrict__ col,
                                                   int* __restrict__ row_start,
                                                   int* __restrict__ deg) {
    __shared__ int cnt[256];
    __shared__ int sh[256];
    __shared__ int cur[256];
    int tid = threadIdx.x, b = blockIdx.x;
    int bs = bstart[b], be = bstart[b + 1];
    cnt[tid] = 0;
    __syncthreads();
    for (int e = bs + tid; e < be; e += 256)
        atomicAdd(&cnt[(esv[e] >> 17) & 255], 1);
    __syncthreads();
    int v = cnt[tid];
    sh[tid] = v;
    __syncthreads();
    for (int o = 1; o < 256; o <<= 1) {
        int t = (tid >= o) ? sh[tid - o] : 0;
        __syncthreads();
        sh[tid] += t;
        __syncthreads();
    }
    int off  = sh[tid] - v;
    int node = (b << 8) + tid;
    if (node < N_NODES) {
        row_start[node] = bs + off;
        deg[node]       = v;
    }
    cur[tid] = bs + off;
    __syncthreads();
    for (int e = bs + tid; e < be; e += 256) {
        int pk  = esv[e];
        int nd  = (pk >> 17) & 255;
        int pos = atomicAdd(&cur[nd], 1);
        col[pos] = pk & 0x1FFFF;
    }
}

// ---------------------------------------------------------------- MFMA GEMM
// R16: 64-row tile (grid 782x3, was 1563x3). LDS 52 KB -> still 3 blocks/CU,
// but half the block count => half the total B-staging traffic and 2x the
// MFMA:LDS-read ratio (32 MFMAs per 24 b128 reads vs 16 per 16).
__global__ __launch_bounds__(256) void gemm3m_kernel(
        const __half* __restrict__ Xh,   // [N][128] fp16
        const __half* __restrict__ WTl,  // [3][128 n][128 k] fp16, this layer
        const float* __restrict__ bd, const float* __restrict__ bc,
        const float* __restrict__ bs,
        __half* __restrict__ Od, __half* __restrict__ Oc,
        __half* __restrict__ Sh) {
    __shared__ _Float16 As[64 * LDK];
    __shared__ _Float16 Bs[128 * LDK];

    const int tid = threadIdx.x;
    const int m0  = blockIdx.x * 64;
    const int w   = blockIdx.y;

    // stage A: 64 rows x 128 halves = 1024 uint4 (4/thread)
#pragma unroll
    for (int i = 0; i < 4; ++i) {
        int c    = i * 256 + tid;
        int row  = c >> 4;
        int colh = (c & 15) * 8;
        uint4 v  = make_uint4(0u, 0u, 0u, 0u);
        int gr   = m0 + row;
        if (gr < N_NODES) v = *(const uint4*)(Xh + (size_t)gr * DIM + colh);
        *(uint4*)(As + row * LDK + colh) = v;
    }
    // stage B^T: 128 rows x 128 halves = 2048 uint4 (8/thread)
    {
        const __half* Wt = WTl + (size_t)w * DIM * DIM;
#pragma unroll
        for (int i = 0; i < 8; ++i) {
            int c    = i * 256 + tid;
            int row  = c >> 4;
            int colh = (c & 15) * 8;
            uint4 v = *(const uint4*)(Wt + (size_t)row * DIM + colh);
            *(uint4*)(Bs + row * LDK + colh) = v;
        }
    }
    __syncthreads();

    const int wv = tid >> 6;     // wave -> cols wv*32..wv*32+31
    const int l  = tid & 63;
    const int lm = l & 15;
    const int q  = l >> 4;

    const float* bias = (w == 0) ? bd : (w == 1) ? bc : bs;
    float b0v = bias[wv * 32 + lm];
    float b1v = bias[wv * 32 + 16 + lm];
    f32x4 acc[4][2];
#pragma unroll
    for (int mt = 0; mt < 4; ++mt) {
        acc[mt][0] = (f32x4){b0v, b0v, b0v, b0v};
        acc[mt][1] = (f32x4){b1v, b1v, b1v, b1v};
    }

#pragma unroll
    for (int ks = 0; ks < 4; ++ks) {
        int coff = ks * 32 + q * 8;
        half8 am[4];
#pragma unroll
        for (int mt = 0; mt < 4; ++mt)
            am[mt] = *(const half8*)(As + (mt * 16 + lm) * LDK + coff);
        half8 bb0 = *(const half8*)(Bs + (wv * 32 + lm) * LDK + coff);
        half8 bb1 = *(const half8*)(Bs + (wv * 32 + 16 + lm) * LDK + coff);
#pragma unroll
        for (int mt = 0; mt < 4; ++mt) {
            acc[mt][0] = __builtin_amdgcn_mfma_f32_16x16x32_f16(am[mt], bb0, acc[mt][0], 0, 0, 0);
            acc[mt][1] = __builtin_amdgcn_mfma_f32_16x16x32_f16(am[mt], bb1, acc[mt][1], 0, 0, 0);
        }
    }

    __half* O = (w == 0) ? Od : (w == 1) ? Oc : Sh;
#pragma unroll
    for (int mt = 0; mt < 4; ++mt)
#pragma unroll
        for (int nt = 0; nt < 2; ++nt) {
            int colg = wv * 32 + nt * 16 + lm;
#pragma unroll
            for (int r = 0; r < 4; ++r) {
                int row = m0 + mt * 16 + q * 4 + r;
                if (row < N_NODES)
                    O[(size_t)row * DIM + colg] = __float2half(acc[mt][nt][r]);
            }
        }
}

// ---------------------------------------------------------------- aggregation
// R13-proven floor: half-wave (32 lanes) per node, fp16 rows (256 B), 8-deep
// bursts with clamped+masked tail. 3.4 TB/s, ~91% BW-bound — structural.
__global__ __launch_bounds__(256) void agg_kernel(
        const int* __restrict__ row_start, const int* __restrict__ deg_arr,
        const int* __restrict__ col,
        const __half* __restrict__ Xdc,
        const __half* __restrict__ Sh, __half* __restrict__ Xout) {
    int wave = (blockIdx.x * 256 + threadIdx.x) >> 6;
    int lane = threadIdx.x & 63;
    int half = lane >> 5;
    int l32  = lane & 31;
    int node = wave * 2 + half;
    if (node >= N_NODES) return;

    int rs  = row_start[node];
    int deg = deg_arr[node];
    const size_t off = (size_t)l32 * 4;   // in halves

    float4 a[8];
#pragma unroll
    for (int i = 0; i < 8; ++i) a[i] = make_float4(0.f, 0.f, 0.f, 0.f);

    if (deg > 0) {
        int dgm1 = deg - 1;
        int nb   = (deg + 7) >> 3;
        for (int b = 0; b < nb; ++b) {
            int e0 = b * 8;
            int p[8];
#pragma unroll
            for (int i = 0; i < 8; ++i) {
                int idx = e0 + i;
                p[i] = col[rs + (idx < deg ? idx : dgm1)];
            }
            union { uint2 u; __half2 h2[2]; } v[8];
#pragma unroll
            for (int i = 0; i < 8; ++i)
                v[i].u = *(const uint2*)(Xdc + (size_t)p[i] * DIM + off);
#pragma unroll
            for (int i = 0; i < 8; ++i) {
                if (e0 + i >= deg) { v[i].u.x = 0u; v[i].u.y = 0u; }
            }
#pragma unroll
            for (int i = 0; i < 8; ++i) {
                float2 f0 = __half22float2(v[i].h2[0]);
                float2 f1 = __half22float2(v[i].h2[1]);
                a[i].x += f0.x; a[i].y += f0.y;
                a[i].z += f1.x; a[i].w += f1.y;
            }
        }
    }

#pragma unroll
    for (int i = 1; i < 8; ++i) {
        a[0].x += a[i].x; a[0].y += a[i].y;
        a[0].z += a[i].z; a[0].w += a[i].w;
    }

    union { uint2 u; __half2 h2[2]; } sv;
    sv.u = *(const uint2*)(Sh + (size_t)node * DIM + off);
    float2 s0 = __half22float2(sv.h2[0]);
    float2 s1 = __half22float2(sv.h2[1]);

    float rx = fmaxf(a[0].x + s0.x, 0.f);
    float ry = fmaxf(a[0].y + s0.y, 0.f);
    float rz = fmaxf(a[0].z + s1.x, 0.f);
    float rw = fmaxf(a[0].w + s1.y, 0.f);

    union { __half2 h2[2]; uint2 u; } pk;
    pk.h2[0] = __floats2half2_rn(rx, ry);
    pk.h2[1] = __floats2half2_rn(rz, rw);
    *(uint2*)(Xout + (size_t)node * DIM + off) = pk.u;
}

// ---------------------------------------------------------------- pooling
// R13-proven: 782 blocks, 8 row-streams x 32 lanes, uint2 loads, LDS bucket
// flush. NO device-scope fence (R12/R13 lesson: per-block __threadfence()
// across a 782-block grid costs ~50us). div is its own launch.
__global__ __launch_bounds__(256) void pool_kernel(const __half* __restrict__ X,
                                                   const int* __restrict__ bid,
                                                   float* __restrict__ sums,
                                                   int* __restrict__ gcnt) {
    __shared__ float acc[8][DIM];
    __shared__ int scnt[8];
    __shared__ int sgmin;
    int tid = threadIdx.x;
    for (int i = tid; i < 8 * DIM; i += 256) ((float*)acc)[i] = 0.f;
    if (tid < 8) scnt[tid] = 0;
    int n0 = blockIdx.x * 64;
    if (tid == 0) sgmin = bid[n0];
    __syncthreads();
    int gmin = sgmin;

    int s    = tid >> 5;
    int lane = tid & 31;
    int r0   = n0 + s * 8;

    int g[8];
    union { uint2 u; __half2 h2[2]; } v[8];
#pragma unroll
    for (int i = 0; i < 8; ++i) {
        int r = r0 + i;
        g[i] = (r < N_NODES) ? bid[r] : -1;
    }
#pragma unroll
    for (int i = 0; i < 8; ++i) {
        int r = r0 + i;
        if (r < N_NODES)
            v[i].u = *(const uint2*)(X + (size_t)r * DIM + lane * 4);
        else { v[i].u.x = 0u; v[i].u.y = 0u; }
    }

    float4 a = make_float4(0.f, 0.f, 0.f, 0.f);
    int cur = -1, run = 0;
#pragma unroll
    for (int i = 0; i < 8; ++i) {
        if (g[i] != cur) {
            if (cur >= 0) {
                int slot = cur - gmin;
                if (slot < 8) {
                    atomicAdd(&acc[slot][lane * 4 + 0], a.x);
                    atomicAdd(&acc[slot][lane * 4 + 1], a.y);
                    atomicAdd(&acc[slot][lane * 4 + 2], a.z);
                    atomicAdd(&acc[slot][lane * 4 + 3], a.w);
                    if (lane == 0) atomicAdd(&scnt[slot], run);
                } else {
                    atomicAdd(&sums[cur * DIM + lane * 4 + 0], a.x);
                    atomicAdd(&sums[cur * DIM + lane * 4 + 1], a.y);
                    atomicAdd(&sums[cur * DIM + lane * 4 + 2], a.z);
                    atomicAdd(&sums[cur * DIM + lane * 4 + 3], a.w);
                    if (lane == 0) atomicAdd(&gcnt[cur], run);
                }
            }
            cur = g[i];
            a = make_float4(0.f, 0.f, 0.f, 0.f);
            run = 0;
        }
        if (g[i] >= 0) {
            float2 f0 = __half22float2(v[i].h2[0]);
            float2 f1 = __half22float2(v[i].h2[1]);
            a.x += f0.x; a.y += f0.y; a.z += f1.x; a.w += f1.y;
            run++;
        }
    }
    if (cur >= 0) {
        int slot = cur - gmin;
        if (slot < 8) {
            atomicAdd(&acc[slot][lane * 4 + 0], a.x);
            atomicAdd(&acc[slot][lane * 4 + 1], a.y);
            atomicAdd(&acc[slot][lane * 4 + 2], a.z);
            atomicAdd(&acc[slot][lane * 4 + 3], a.w);
            if (lane == 0) atomicAdd(&scnt[slot], run);
        } else {
            atomicAdd(&sums[cur * DIM + lane * 4 + 0], a.x);
            atomicAdd(&sums[cur * DIM + lane * 4 + 1], a.y);
            atomicAdd(&sums[cur * DIM + lane * 4 + 2], a.z);
            atomicAdd(&sums[cur * DIM + lane * 4 + 3], a.w);
            if (lane == 0) atomicAdd(&gcnt[cur], run);
        }
    }
    __syncthreads();

    for (int slot = 0; slot < 8; ++slot) {
        if (scnt[slot] > 0) {
            int gg = gmin + slot;
            for (int i = tid; i < DIM; i += 256)
                atomicAdd(&sums[gg * DIM + i], acc[slot][i]);
            if (tid == 0) atomicAdd(&gcnt[gg], scnt[slot]);
        }
    }
}

__global__ __launch_bounds__(256) void div_kernel(const float* __restrict__ sums,
                                                  const int* __restrict__ gcnt,
                                                  float* __restrict__ out) {
    int i = blockIdx.x * 256 + threadIdx.x;
    if (i < NGRAPHS * DIM) {
        int g = i >> 7;
        out[i] = sums[i] / fmaxf((float)gcnt[g], 1.f);
    }
}

// ---------------------------------------------------------------- launcher
extern "C" void kernel_launch(void* const* d_in, const int* in_sizes, int n_in,
                              void* d_out, int out_size, void* d_ws, size_t ws_size,
                              hipStream_t stream) {
    const float* Xin = (const float*)d_in[0];
    const float* Wd  = (const float*)d_in[1];
    const float* bd  = (const float*)d_in[2];
    const float* Wc  = (const float*)d_in[3];
    const float* bc  = (const float*)d_in[4];
    const float* Ws  = (const float*)d_in[5];
    const float* bs  = (const float*)d_in[6];
    const int* edge_index = (const int*)d_in[7];
    const int* edge_types = (const int*)d_in[8];
    const int* batch_ids  = (const int*)d_in[9];

    const int* src = edge_index;
    const int* dst = edge_index + N_EDGES;

    const size_t NBH = (size_t)N_NODES * DIM * sizeof(__half);  // 12.8 MB
    char* w = (char*)d_ws;
    auto take = [&](size_t bytes) {
        char* p = w;
        w += (bytes + 255) & ~(size_t)255;
        return p;
    };
    __half* X0h  = (__half*)take(NBH);
    __half* Xb0h = (__half*)take(NBH);
    __half* Xb1h = (__half*)take(NBH);
    __half* Xdc  = (__half*)take(2 * NBH);  // rows 0..N = Xd, N..2N = Xc
    __half* Shb  = (__half*)take(NBH);
    __half* WT   = (__half*)take((size_t)9 * DIM * DIM * sizeof(__half));
    int* col     = (int*)take((size_t)N_EDGES * 4);
    int* esv     = (int*)take((size_t)N_EDGES * 4);
    int* cntmat  = (int*)take((size_t)NBUCK * CSR_BLKS * 4);
    int* exc     = (int*)take((size_t)NBUCK * CSR_BLKS * 4);
    int* btot    = (int*)take((size_t)NBUCK * 4);
    int* bstart  = (int*)take((size_t)(NBUCK + 1) * 4);
    int* rowst   = (int*)take((size_t)N_NODES * 4);
    int* deg     = (int*)take((size_t)N_NODES * 4);
    float* sums  = (float*)take((size_t)NGRAPHS * DIM * 4);
    int* gcnt    = (int*)take(NGRAPHS * 4);

    setup_kernel<<<(N_NODES * DIM / 4 + 255) / 256, 256, 0, stream>>>(
        Xin, X0h, Wd, Wc, Ws, WT, sums, gcnt);

    csr1_kernel<<<CSR_BLKS, 256, 0, stream>>>(dst, cntmat);
    scanA_kernel<<<NBUCK, 256, 0, stream>>>(cntmat, exc, btot);
    csr2_kernel<<<CSR_BLKS, 256, 0, stream>>>(src, dst, edge_types, exc,
                                              btot, bstart, esv);
    csr3_kernel<<<NBUCK, 256, 0, stream>>>(esv, bstart, col, rowst, deg);

    const int GEMM_MBLK = (N_NODES + 63) / 64;    // 782
    const int AGG_BLKS  = (N_NODES / 2 + 3) / 4;  // 6250 (2 nodes/wave)
    const __half* Xcur = X0h;
    __half* bufs[3] = {Xb0h, Xb1h, Xb0h};
    for (int l = 0; l < NLAYERS; ++l) {
        gemm3m_kernel<<<dim3(GEMM_MBLK, 3), 256, 0, stream>>>(
            Xcur, WT + (size_t)l * 3 * DIM * DIM,
            bd + (size_t)l * DIM, bc + (size_t)l * DIM, bs + (size_t)l * DIM,
            Xdc, Xdc + (size_t)N_NODES * DIM, Shb);
        __half* Xnext = bufs[l];
        agg_kernel<<<AGG_BLKS, 256, 0, stream>>>(rowst, deg, col, Xdc, Shb, Xnext);
        Xcur = Xnext;
    }

    const int POOL_BLKS = (N_NODES + 63) / 64;  // 782
    pool_kernel<<<POOL_BLKS, 256, 0, stream>>>(Xcur, batch_ids, sums, gcnt);
    div_kernel<<<(NGRAPHS * DIM + 255) / 256, 256, 0, stream>>>(sums, gcnt,
                                                                (float*)d_out);
}

// Round 17
// 315.298 us; speedup vs baseline: 1.3688x; 1.2232x over previous
//
#include <hip/hip_runtime.h>
#include <hip/hip_fp16.h>

#define N_NODES 50000
#define N_EDGES 1600000
#define DIM     128
#define NLAYERS 3
#define NGRAPHS 64

#define NBUCK   196            // buckets of 256 nodes: bucket = dst >> 8
#define CSR_BLKS 256
#define EPB     (N_EDGES / CSR_BLKS)   // 6250 edges per csr block
#define EITER   ((EPB + 255) / 256)    // 25

typedef _Float16 half8 __attribute__((ext_vector_type(8)));
typedef float    f32x4 __attribute__((ext_vector_type(4)));
typedef float    f32x2 __attribute__((ext_vector_type(2)));

#define LDK 136   // padded halves/row: 272B stride (16B-aligned), rotates banks

// fp8 e4m3 scalar convert (HW cvt, RNE)
__device__ __forceinline__ unsigned char f32_to_fp8(float v) {
    int q = __builtin_amdgcn_cvt_pk_fp8_f32(v, v, 0, false);
    return (unsigned char)(q & 0xFF);
}

// ---------------------------------------------------------------- setup
__global__ __launch_bounds__(256) void setup_kernel(
        const float* __restrict__ X, __half* __restrict__ Xh,
        const float* __restrict__ Wd, const float* __restrict__ Wc,
        const float* __restrict__ Ws, __half* __restrict__ WT,
        float* __restrict__ sums, int* __restrict__ gcnt) {
    int i = blockIdx.x * 256 + threadIdx.x;
    if (i < N_NODES * DIM / 4) {
        float4 v = *(const float4*)(X + (size_t)i * 4);
        union { __half2 h2[2]; uint2 u; } pk;
        pk.h2[0] = __floats2half2_rn(v.x, v.y);
        pk.h2[1] = __floats2half2_rn(v.z, v.w);
        *(uint2*)(Xh + (size_t)i * 4) = pk.u;
    }
    if (i < 9 * DIM * DIM) {   // WT[(l*3+w)][n][k] = W[l][k][n]
        int k  = i & 127;
        int n  = (i >> 7) & 127;
        int lw = i >> 14;
        int l  = lw / 3, w = lw - 3 * l;
        const float* W = ((w == 0) ? Wd : (w == 1) ? Wc : Ws)
                         + (size_t)l * DIM * DIM;
        WT[i] = __float2half(W[k * DIM + n]);
    }
    if (i < NGRAPHS * DIM) sums[i] = 0.f;
    if (i < NGRAPHS) gcnt[i] = 0;
}

// ---------------------------------------------------------------- CSR build
// Two-level counting sort, zero global atomics (R7 lesson: 1.6M device
// atomics cost 56 MB HBM RMW regardless of locality).
__global__ __launch_bounds__(256) void csr1_kernel(const int* __restrict__ dst,
                                                   int* __restrict__ cntmat) {
    __shared__ int hc[NBUCK];
    int tid = threadIdx.x;
    for (int i = tid; i < NBUCK; i += 256) hc[i] = 0;
    __syncthreads();
    int base = blockIdx.x * EPB;
#pragma unroll
    for (int i = 0; i < EITER; ++i) {
        int idx = i * 256 + tid;
        if (idx < EPB) atomicAdd(&hc[dst[base + idx] >> 8], 1);
    }
    __syncthreads();
    for (int i = tid; i < NBUCK; i += 256)
        cntmat[i * CSR_BLKS + blockIdx.x] = hc[i];
}

__global__ __launch_bounds__(256) void scanA_kernel(const int* __restrict__ cntmat,
                                                    int* __restrict__ exc,
                                                    int* __restrict__ btot) {
    __shared__ int sh[256];
    int tid = threadIdx.x, b = blockIdx.x;
    int v = cntmat[b * CSR_BLKS + tid];
    sh[tid] = v;
    __syncthreads();
    for (int o = 1; o < 256; o <<= 1) {
        int t = (tid >= o) ? sh[tid - o] : 0;
        __syncthreads();
        sh[tid] += t;
        __syncthreads();
    }
    exc[b * CSR_BLKS + tid] = sh[tid] - v;
    if (tid == 255) btot[b] = sh[255];
}

// scanB folded in; edge record packed into ONE int (R16):
// sv = src + et*N (17 bits) | (dst&255)<<17.
__global__ __launch_bounds__(256) void csr2_kernel(const int* __restrict__ src,
                                                   const int* __restrict__ dst,
                                                   const int* __restrict__ et,
                                                   const int* __restrict__ exc,
                                                   const int* __restrict__ btot,
                                                   int* __restrict__ bstart,
                                                   int* __restrict__ esv) {
    __shared__ int sh[256];
    __shared__ int bst[NBUCK];
    __shared__ int cur[NBUCK];
    int tid = threadIdx.x;
    int v = (tid < NBUCK) ? btot[tid] : 0;
    sh[tid] = v;
    __syncthreads();
    for (int o = 1; o < 256; o <<= 1) {
        int t = (tid >= o) ? sh[tid - o] : 0;
        __syncthreads();
        sh[tid] += t;
        __syncthreads();
    }
    if (tid < NBUCK) bst[tid] = sh[tid] - v;
    if (blockIdx.x == 0) {
        if (tid < NBUCK) bstart[tid] = sh[tid] - v;
        if (tid == NBUCK - 1) bstart[NBUCK] = sh[tid];
    }
    __syncthreads();
    if (tid < NBUCK) cur[tid] = exc[tid * CSR_BLKS + blockIdx.x] + bst[tid];
    __syncthreads();
    int base = blockIdx.x * EPB;
#pragma unroll
    for (int i = 0; i < EITER; ++i) {
        int idx = i * 256 + tid;
        if (idx < EPB) {
            int e = base + idx;
            int d = dst[e];
            int pos = atomicAdd(&cur[d >> 8], 1);
            esv[pos] = (src[e] + et[e] * N_NODES) | ((d & 255) << 17);
        }
    }
}

// phase 4: per-bucket finalize (LDS count -> scan -> row_start/deg -> scatter)
__global__ __launch_bounds__(256) void csr3_kernel(const int* __restrict__ esv,
                                                   const int* __restrict__ bstart,
                                                   int* __restrict__ col,
                                                   int* __restrict__ row_start,
                                                   int* __restrict__ deg) {
    __shared__ int cnt[256];
    __shared__ int sh[256];
    __shared__ int cur[256];
    int tid = threadIdx.x, b = blockIdx.x;
    int bs = bstart[b], be = bstart[b + 1];
    cnt[tid] = 0;
    __syncthreads();
    for (int e = bs + tid; e < be; e += 256)
        atomicAdd(&cnt[(esv[e] >> 17) & 255], 1);
    __syncthreads();
    int v = cnt[tid];
    sh[tid] = v;
    __syncthreads();
    for (int o = 1; o < 256; o <<= 1) {
        int t = (tid >= o) ? sh[tid - o] : 0;
        __syncthreads();
        sh[tid] += t;
        __syncthreads();
    }
    int off  = sh[tid] - v;
    int node = (b << 8) + tid;
    if (node < N_NODES) {
        row_start[node] = bs + off;
        deg[node]       = v;
    }
    cur[tid] = bs + off;
    __syncthreads();
    for (int e = bs + tid; e < be; e += 256) {
        int pk  = esv[e];
        int nd  = (pk >> 17) & 255;
        int pos = atomicAdd(&cur[nd], 1);
        col[pos] = pk & 0x1FFFF;
    }
}

// ---------------------------------------------------------------- MFMA GEMM
// R16 64-row tile. R17: Od/Oc stored as fp8 e4m3 (halves the agg gather
// source: Xdc 25.6 -> 12.8 MB; per-XCD duplication floor 205 -> 102 MB).
// Sh (self term, streamed once by agg) stays fp16.
__global__ __launch_bounds__(256) void gemm3m_kernel(
        const __half* __restrict__ Xh,   // [N][128] fp16
        const __half* __restrict__ WTl,  // [3][128 n][128 k] fp16, this layer
        const float* __restrict__ bd, const float* __restrict__ bc,
        const float* __restrict__ bs,
        unsigned char* __restrict__ Od, unsigned char* __restrict__ Oc,
        __half* __restrict__ Sh) {
    __shared__ _Float16 As[64 * LDK];
    __shared__ _Float16 Bs[128 * LDK];

    const int tid = threadIdx.x;
    const int m0  = blockIdx.x * 64;
    const int w   = blockIdx.y;

#pragma unroll
    for (int i = 0; i < 4; ++i) {
        int c    = i * 256 + tid;
        int row  = c >> 4;
        int colh = (c & 15) * 8;
        uint4 v  = make_uint4(0u, 0u, 0u, 0u);
        int gr   = m0 + row;
        if (gr < N_NODES) v = *(const uint4*)(Xh + (size_t)gr * DIM + colh);
        *(uint4*)(As + row * LDK + colh) = v;
    }
    {
        const __half* Wt = WTl + (size_t)w * DIM * DIM;
#pragma unroll
        for (int i = 0; i < 8; ++i) {
            int c    = i * 256 + tid;
            int row  = c >> 4;
            int colh = (c & 15) * 8;
            uint4 v = *(const uint4*)(Wt + (size_t)row * DIM + colh);
            *(uint4*)(Bs + row * LDK + colh) = v;
        }
    }
    __syncthreads();

    const int wv = tid >> 6;
    const int l  = tid & 63;
    const int lm = l & 15;
    const int q  = l >> 4;

    const float* bias = (w == 0) ? bd : (w == 1) ? bc : bs;
    float b0v = bias[wv * 32 + lm];
    float b1v = bias[wv * 32 + 16 + lm];
    f32x4 acc[4][2];
#pragma unroll
    for (int mt = 0; mt < 4; ++mt) {
        acc[mt][0] = (f32x4){b0v, b0v, b0v, b0v};
        acc[mt][1] = (f32x4){b1v, b1v, b1v, b1v};
    }

#pragma unroll
    for (int ks = 0; ks < 4; ++ks) {
        int coff = ks * 32 + q * 8;
        half8 am[4];
#pragma unroll
        for (int mt = 0; mt < 4; ++mt)
            am[mt] = *(const half8*)(As + (mt * 16 + lm) * LDK + coff);
        half8 bb0 = *(const half8*)(Bs + (wv * 32 + lm) * LDK + coff);
        half8 bb1 = *(const half8*)(Bs + (wv * 32 + 16 + lm) * LDK + coff);
#pragma unroll
        for (int mt = 0; mt < 4; ++mt) {
            acc[mt][0] = __builtin_amdgcn_mfma_f32_16x16x32_f16(am[mt], bb0, acc[mt][0], 0, 0, 0);
            acc[mt][1] = __builtin_amdgcn_mfma_f32_16x16x32_f16(am[mt], bb1, acc[mt][1], 0, 0, 0);
        }
    }

    if (w < 2) {
        unsigned char* O = (w == 0) ? Od : Oc;
#pragma unroll
        for (int mt = 0; mt < 4; ++mt)
#pragma unroll
            for (int nt = 0; nt < 2; ++nt) {
                int colg = wv * 32 + nt * 16 + lm;
#pragma unroll
                for (int r = 0; r < 4; ++r) {
                    int row = m0 + mt * 16 + q * 4 + r;
                    if (row < N_NODES)
                        O[(size_t)row * DIM + colg] = f32_to_fp8(acc[mt][nt][r]);
                }
            }
    } else {
#pragma unroll
        for (int mt = 0; mt < 4; ++mt)
#pragma unroll
            for (int nt = 0; nt < 2; ++nt) {
                int colg = wv * 32 + nt * 16 + lm;
#pragma unroll
                for (int r = 0; r < 4; ++r) {
                    int row = m0 + mt * 16 + q * 4 + r;
                    if (row < N_NODES)
                        Sh[(size_t)row * DIM + colg] = __float2half(acc[mt][nt][r]);
                }
            }
    }
}

// ---------------------------------------------------------------- aggregation
// R13 structure (half-wave per node, 8-deep clamped+masked bursts) with fp8
// message rows: lane loads uint = 4 fp8 (row = 128 B, 2 cache lines), HW
// cvt_pk_f32_fp8 to fp32, accumulate fp32. S fp16, output X fp16.
__global__ __launch_bounds__(256) void agg_kernel(
        const int* __restrict__ row_start, const int* __restrict__ deg_arr,
        const int* __restrict__ col,
        const unsigned char* __restrict__ Xdc,
        const __half* __restrict__ Sh, __half* __restrict__ Xout) {
    int wave = (blockIdx.x * 256 + threadIdx.x) >> 6;
    int lane = threadIdx.x & 63;
    int half = lane >> 5;
    int l32  = lane & 31;
    int node = wave * 2 + half;
    if (node >= N_NODES) return;

    int rs  = row_start[node];
    int deg = deg_arr[node];
    const size_t off = (size_t)l32 * 4;   // in fp8 bytes (4 cols/lane)

    float4 a[8];
#pragma unroll
    for (int i = 0; i < 8; ++i) a[i] = make_float4(0.f, 0.f, 0.f, 0.f);

    if (deg > 0) {
        int dgm1 = deg - 1;
        int nb   = (deg + 7) >> 3;
        for (int b = 0; b < nb; ++b) {
            int e0 = b * 8;
            int p[8];
#pragma unroll
            for (int i = 0; i < 8; ++i) {
                int idx = e0 + i;
                p[i] = col[rs + (idx < deg ? idx : dgm1)];
            }
            unsigned int v[8];
#pragma unroll
            for (int i = 0; i < 8; ++i)
                v[i] = *(const unsigned int*)(Xdc + (size_t)p[i] * DIM + off);
#pragma unroll
            for (int i = 0; i < 8; ++i) {
                if (e0 + i >= deg) v[i] = 0u;   // e4m3 0x00 == +0.0
            }
#pragma unroll
            for (int i = 0; i < 8; ++i) {
                f32x2 f0 = __builtin_amdgcn_cvt_pk_f32_fp8(v[i], false);
                f32x2 f1 = __builtin_amdgcn_cvt_pk_f32_fp8(v[i], true);
                a[i].x += f0[0]; a[i].y += f0[1];
                a[i].z += f1[0]; a[i].w += f1[1];
            }
        }
    }

#pragma unroll
    for (int i = 1; i < 8; ++i) {
        a[0].x += a[i].x; a[0].y += a[i].y;
        a[0].z += a[i].z; a[0].w += a[i].w;
    }

    union { uint2 u; __half2 h2[2]; } sv;
    sv.u = *(const uint2*)(Sh + (size_t)node * DIM + off);
    float2 s0 = __half22float2(sv.h2[0]);
    float2 s1 = __half22float2(sv.h2[1]);

    float rx = fmaxf(a[0].x + s0.x, 0.f);
    float ry = fmaxf(a[0].y + s0.y, 0.f);
    float rz = fmaxf(a[0].z + s1.x, 0.f);
    float rw = fmaxf(a[0].w + s1.y, 0.f);

    union { __half2 h2[2]; uint2 u; } pk;
    pk.h2[0] = __floats2half2_rn(rx, ry);
    pk.h2[1] = __floats2half2_rn(rz, rw);
    *(uint2*)(Xout + (size_t)node * DIM + off) = pk.u;
}

// ---------------------------------------------------------------- pooling
// R13-proven; NO device-scope fence (R12/R13 lesson: ~50us per 782-block
// grid). div is its own launch.
__global__ __launch_bounds__(256) void pool_kernel(const __half* __restrict__ X,
                                                   const int* __restrict__ bid,
                                                   float* __restrict__ sums,
                                                   int* __restrict__ gcnt) {
    __shared__ float acc[8][DIM];
    __shared__ int scnt[8];
    __shared__ int sgmin;
    int tid = threadIdx.x;
    for (int i = tid; i < 8 * DIM; i += 256) ((float*)acc)[i] = 0.f;
    if (tid < 8) scnt[tid] = 0;
    int n0 = blockIdx.x * 64;
    if (tid == 0) sgmin = bid[n0];
    __syncthreads();
    int gmin = sgmin;

    int s    = tid >> 5;
    int lane = tid & 31;
    int r0   = n0 + s * 8;

    int g[8];
    union { uint2 u; __half2 h2[2]; } v[8];
#pragma unroll
    for (int i = 0; i < 8; ++i) {
        int r = r0 + i;
        g[i] = (r < N_NODES) ? bid[r] : -1;
    }
#pragma unroll
    for (int i = 0; i < 8; ++i) {
        int r = r0 + i;
        if (r < N_NODES)
            v[i].u = *(const uint2*)(X + (size_t)r * DIM + lane * 4);
        else { v[i].u.x = 0u; v[i].u.y = 0u; }
    }

    float4 a = make_float4(0.f, 0.f, 0.f, 0.f);
    int cur = -1, run = 0;
#pragma unroll
    for (int i = 0; i < 8; ++i) {
        if (g[i] != cur) {
            if (cur >= 0) {
                int slot = cur - gmin;
                if (slot < 8) {
                    atomicAdd(&acc[slot][lane * 4 + 0], a.x);
                    atomicAdd(&acc[slot][lane * 4 + 1], a.y);
                    atomicAdd(&acc[slot][lane * 4 + 2], a.z);
                    atomicAdd(&acc[slot][lane * 4 + 3], a.w);
                    if (lane == 0) atomicAdd(&scnt[slot], run);
                } else {
                    atomicAdd(&sums[cur * DIM + lane * 4 + 0], a.x);
                    atomicAdd(&sums[cur * DIM + lane * 4 + 1], a.y);
                    atomicAdd(&sums[cur * DIM + lane * 4 + 2], a.z);
                    atomicAdd(&sums[cur * DIM + lane * 4 + 3], a.w);
                    if (lane == 0) atomicAdd(&gcnt[cur], run);
                }
            }
            cur = g[i];
            a = make_float4(0.f, 0.f, 0.f, 0.f);
            run = 0;
        }
        if (g[i] >= 0) {
            float2 f0 = __half22float2(v[i].h2[0]);
            float2 f1 = __half22float2(v[i].h2[1]);
            a.x += f0.x; a.y += f0.y; a.z += f1.x; a.w += f1.y;
            run++;
        }
    }
    if (cur >= 0) {
        int slot = cur - gmin;
        if (slot < 8) {
            atomicAdd(&acc[slot][lane * 4 + 0], a.x);
            atomicAdd(&acc[slot][lane * 4 + 1], a.y);
            atomicAdd(&acc[slot][lane * 4 + 2], a.z);
            atomicAdd(&acc[slot][lane * 4 + 3], a.w);
            if (lane == 0) atomicAdd(&scnt[slot], run);
        } else {
            atomicAdd(&sums[cur * DIM + lane * 4 + 0], a.x);
            atomicAdd(&sums[cur * DIM + lane * 4 + 1], a.y);
            atomicAdd(&sums[cur * DIM + lane * 4 + 2], a.z);
            atomicAdd(&sums[cur * DIM + lane * 4 + 3], a.w);
            if (lane == 0) atomicAdd(&gcnt[cur], run);
        }
    }
    __syncthreads();

    for (int slot = 0; slot < 8; ++slot) {
        if (scnt[slot] > 0) {
            int gg = gmin + slot;
            for (int i = tid; i < DIM; i += 256)
                atomicAdd(&sums[gg * DIM + i], acc[slot][i]);
            if (tid == 0) atomicAdd(&gcnt[gg], scnt[slot]);
        }
    }
}

__global__ __launch_bounds__(256) void div_kernel(const float* __restrict__ sums,
                                                  const int* __restrict__ gcnt,
                                                  float* __restrict__ out) {
    int i = blockIdx.x * 256 + threadIdx.x;
    if (i < NGRAPHS * DIM) {
        int g = i >> 7;
        out[i] = sums[i] / fmaxf((float)gcnt[g], 1.f);
    }
}

// ---------------------------------------------------------------- launcher
extern "C" void kernel_launch(void* const* d_in, const int* in_sizes, int n_in,
                              void* d_out, int out_size, void* d_ws, size_t ws_size,
                              hipStream_t stream) {
    const float* Xin = (const float*)d_in[0];
    const float* Wd  = (const float*)d_in[1];
    const float* bd  = (const float*)d_in[2];
    const float* Wc  = (const float*)d_in[3];
    const float* bc  = (const float*)d_in[4];
    const float* Ws  = (const float*)d_in[5];
    const float* bs  = (const float*)d_in[6];
    const int* edge_index = (const int*)d_in[7];
    const int* edge_types = (const int*)d_in[8];
    const int* batch_ids  = (const int*)d_in[9];

    const int* src = edge_index;
    const int* dst = edge_index + N_EDGES;

    const size_t NBH = (size_t)N_NODES * DIM * sizeof(__half);  // 12.8 MB
    const size_t NB8 = (size_t)N_NODES * DIM;                   // 6.4 MB fp8
    char* w = (char*)d_ws;
    auto take = [&](size_t bytes) {
        char* p = w;
        w += (bytes + 255) & ~(size_t)255;
        return p;
    };
    __half* X0h  = (__half*)take(NBH);
    __half* Xb0h = (__half*)take(NBH);
    __half* Xb1h = (__half*)take(NBH);
    unsigned char* Xdc = (unsigned char*)take(2 * NB8);  // fp8: Xd rows 0..N, Xc N..2N
    __half* Shb  = (__half*)take(NBH);
    __half* WT   = (__half*)take((size_t)9 * DIM * DIM * sizeof(__half));
    int* col     = (int*)take((size_t)N_EDGES * 4);
    int* esv     = (int*)take((size_t)N_EDGES * 4);
    int* cntmat  = (int*)take((size_t)NBUCK * CSR_BLKS * 4);
    int* exc     = (int*)take((size_t)NBUCK * CSR_BLKS * 4);
    int* btot    = (int*)take((size_t)NBUCK * 4);
    int* bstart  = (int*)take((size_t)(NBUCK + 1) * 4);
    int* rowst   = (int*)take((size_t)N_NODES * 4);
    int* deg     = (int*)take((size_t)N_NODES * 4);
    float* sums  = (float*)take((size_t)NGRAPHS * DIM * 4);
    int* gcnt    = (int*)take(NGRAPHS * 4);

    setup_kernel<<<(N_NODES * DIM / 4 + 255) / 256, 256, 0, stream>>>(
        Xin, X0h, Wd, Wc, Ws, WT, sums, gcnt);

    csr1_kernel<<<CSR_BLKS, 256, 0, stream>>>(dst, cntmat);
    scanA_kernel<<<NBUCK, 256, 0, stream>>>(cntmat, exc, btot);
    csr2_kernel<<<CSR_BLKS, 256, 0, stream>>>(src, dst, edge_types, exc,
                                              btot, bstart, esv);
    csr3_kernel<<<NBUCK, 256, 0, stream>>>(esv, bstart, col, rowst, deg);

    const int GEMM_MBLK = (N_NODES + 63) / 64;    // 782
    const int AGG_BLKS  = (N_NODES / 2 + 3) / 4;  // 6250 (2 nodes/wave)
    const __half* Xcur = X0h;
    __half* bufs[3] = {Xb0h, Xb1h, Xb0h};
    for (int l = 0; l < NLAYERS; ++l) {
        gemm3m_kernel<<<dim3(GEMM_MBLK, 3), 256, 0, stream>>>(
            Xcur, WT + (size_t)l * 3 * DIM * DIM,
            bd + (size_t)l * DIM, bc + (size_t)l * DIM, bs + (size_t)l * DIM,
            Xdc, Xdc + NB8, Shb);
        __half* Xnext = bufs[l];
        agg_kernel<<<AGG_BLKS, 256, 0, stream>>>(rowst, deg, col, Xdc, Shb, Xnext);
        Xcur = Xnext;
    }

    const int POOL_BLKS = (N_NODES + 63) / 64;  // 782
    pool_kernel<<<POOL_BLKS, 256, 0, stream>>>(Xcur, batch_ids, sums, gcnt);
    div_kernel<<<(NGRAPHS * DIM + 255) / 256, 256, 0, stream>>>(sums, gcnt,
                                                                (float*)d_out);
}